// Round 9
// baseline (287.531 us; speedup 1.0000x reference)
//
#include <hip/hip_runtime.h>

#define NPTS 65536          // B*N = 32*2048
#define HH 256
#define DIN 131
#define LAT 128
#define STEPS 5
#define DT 0.2f

typedef unsigned int uint;
typedef unsigned short ushort;
typedef __attribute__((ext_vector_type(8))) short short8;
typedef __attribute__((ext_vector_type(4))) float floatx4;
typedef __attribute__((ext_vector_type(4))) uint uintx4;

// Dynamic LDS layout (160256 B total):
//   smWsw   @ 0      : 131072 B  W2 bf16 B-fragments (linear copy of wsw; step-invariant)
//   smW1tab @ 131072 :  23040 B  [s][kt][q] groups of 8 unit-records {wa,wc,ra,ba_s} (16B)
//                                group stride 144B (16B pad -> q-groups hit distinct banks)
//   smW3    @ 154112 :   4096 B  float4[j] = {W3[0][j], W3[1][j], b2[j], 0}
//   redbuf  @ 158208 :   2048 B  8 waves x 16 points x float4 (same-wave RAW only)
#define OFF_W1TAB 131072
#define OFF_W3    154112
#define OFF_RED   158208
#define LDS_TOTAL 160256

__device__ __forceinline__ float tanh_fast(float x) {
    // tanh(x) = 1 - 2/(exp2(2x*log2e)+1); exact at both saturated ends.
    float e = __builtin_amdgcn_exp2f(x * 2.8853900817779268f);
    return 1.0f - 2.0f * __builtin_amdgcn_rcpf(e + 1.0f);
}

__device__ __forceinline__ ushort f2bf(float f) {
    uint u = __builtin_bit_cast(uint, f);
    u += 0x7fffu + ((u >> 16) & 1u);   // RNE
    return (ushort)(u >> 16);
}

// pack two f32 -> 2x bf16 (RNE) in one instruction; lo -> bits[15:0]
__device__ __forceinline__ uint cvt_pk_bf16(float lo, float hi) {
    uint r;
    asm("v_cvt_pk_bf16_f32 %0, %1, %2" : "=v"(r) : "v"(lo), "v"(hi));
    return r;
}

// 16-lane row sum via DPP row_shr chain (VALU pipe). Sum valid in lane 15 of each
// 16-lane row. (Harness-verified r3-r8.)
__device__ __forceinline__ float dpp_sum16(float x) {
    int t;
    t = __builtin_amdgcn_update_dpp(0, __builtin_bit_cast(int, x), 0x111, 0xf, 0xf, true);
    x += __builtin_bit_cast(float, t);
    t = __builtin_amdgcn_update_dpp(0, __builtin_bit_cast(int, x), 0x112, 0xf, 0xf, true);
    x += __builtin_bit_cast(float, t);
    t = __builtin_amdgcn_update_dpp(0, __builtin_bit_cast(int, x), 0x114, 0xf, 0xf, true);
    x += __builtin_bit_cast(float, t);
    t = __builtin_amdgcn_update_dpp(0, __builtin_bit_cast(int, x), 0x118, 0xf, 0xf, true);
    x += __builtin_bit_cast(float, t);
    return x;
}

// ---- prep (r7-identical):
//  a1[b][h] = b1[h] + sum_l z[b][l]*W1[h][3+l]   (t=0 bias)
//  rs[h] = sum_l W1[h][3+l]
//  wsw = W2 as bf16 B-fragments: wsw[((nt*8+kt)*64+lane)*8+j] = W2[nt*16+(lane&15)][kt*32+(lane>>4)*8+j]
__global__ void prep_kernel(const float* __restrict__ z, const float* __restrict__ W1,
                            const float* __restrict__ b1, const float* __restrict__ W2,
                            float* __restrict__ a1, float* __restrict__ rsv,
                            ushort* __restrict__ wsw)
{
    int tid = blockIdx.x * 256 + threadIdx.x;
    if (tid < 8192) {
        int b = tid >> 8, h = tid & 255;
        const float* wrow = W1 + h * DIN;
        const float* zb = z + b * LAT;
        float s = b1[h], r = 0.f;
        for (int l = 0; l < LAT; ++l) { float wv = wrow[3 + l]; s += wv * zb[l]; r += wv; }
        a1[tid] = s;
        if (b == 0) rsv[h] = r;
    } else {
        int t = tid - 8192;                    // 0..8191
        int lane = t & 63, kt = (t >> 6) & 7, nt = t >> 9;
        int n = nt * 16 + (lane & 15);
        int k = kt * 32 + (lane >> 4) * 8;
        const float* src = W2 + n * HH + k;
        ushort* dst = wsw + t * 8;
        #pragma unroll
        for (int j = 0; j < 8; ++j) dst[j] = f2bf(src[j]);
    }
}

// BARRIER-FREE WAVE-COMPLETE DESIGN (r9; r4-r8 postmortems: phases SUM not MAX,
// barrier-locked 2-block lockstep is the plateau).  Each wave owns 16 points and
// builds its MFMA A-fragments DIRECTLY: lane l computes h1/g1 for point (l&15),
// units kt*32+(l>>4)*8+j -- the exact element set it feeds to the MFMA.  No
// layout transpose => no Vb staging, no __syncthreads in the step loop; waves
// free-run all 5 steps.  Wave-complete N=256 (16 n-tiles, 4 acc-passes with
// A-frags held in regs) closes the j-reduction inside the wave (dpp_sum16 +
// same-wave LDS redistribute).  W2 fragments are read from LDS (staged once:
// 128KB; weights are step-invariant) -- full-N per wave from L2 would need
// ~12 TB/s/XCD, over the 4.3 ceiling.
__global__ __launch_bounds__(512, 2) void cnf_kernel(
        const float* __restrict__ xin, const float* __restrict__ W1,
        const float* __restrict__ b2, const float* __restrict__ W3,
        const float* __restrict__ b3, const float* __restrict__ osc,
        const float* __restrict__ a1, const float* __restrict__ rsv,
        const ushort* __restrict__ wsw, float* __restrict__ out)
{
    extern __shared__ __align__(16) char sm[];

    const int tid = threadIdx.x;
    const int lane = tid & 63;
    const int w = tid >> 6;                      // 8 independent waves
    const int r15 = lane & 15;
    const int q = lane >> 4;
    const int blk = blockIdx.x;
    const int b = blk >> 4;                      // 16 blocks per batch (128 pts/block)

    // ---- stage W2 fragments: linear 131072B copy (uint4 x 16 per thread) ----
    {
        uintx4* dst = (uintx4*)sm;
        const uintx4* src = (const uintx4*)wsw;
        #pragma unroll
        for (int i = 0; i < 16; ++i) dst[tid + i * 512] = src[tid + i * 512];
    }
    // ---- stage per-step layer-1 records + W3 projection table ----
    if (tid < HH) {
        const int h = tid;
        const int kt = h >> 5, rem = h & 31, qq = rem >> 3, u = rem & 7;
        const float wa = W1[h * DIN + 0];
        const float wc = W1[h * DIN + 1];
        const float wt = W1[h * DIN + 2];
        const float ra = rsv[h];
        const float ba = a1[b * HH + h];
        #pragma unroll
        for (int s = 0; s < STEPS; ++s) {
            float* rec = (float*)(sm + OFF_W1TAB + s * 4608 + kt * 576 + qq * 144 + u * 16);
            rec[0] = wa; rec[1] = wc; rec[2] = ra; rec[3] = ba + wt * ((float)s * DT);
        }
        float* w3r = (float*)(sm + OFF_W3 + h * 16);
        w3r[0] = W3[h]; w3r[1] = W3[HH + h]; w3r[2] = b2[h]; w3r[3] = 0.f;
    }

    // ---- per-lane state: point (l&15), replicated across the 4 quads ----
    const int gp = blk * 128 + w * 16 + r15;
    float x0 = xin[gp * 2 + 0];
    float x1 = xin[gp * 2 + 1];
    float cc = 0.f;
    const float osdt = osc[0] * DT;
    const float b30 = b3[0], b31 = b3[1];

    __syncthreads();                             // the ONLY barrier

    const char* wtab  = sm + OFF_W1TAB + q * 144;        // this quad's records
    const char* bbase = sm + (size_t)lane * 16;          // B-frag per-lane base
    float4* red = (float4*)(sm + OFF_RED) + w * 16;      // per-wave scratch

    for (int s = 0; s < STEPS; ++s) {
        // ---- A-build: 3 streams x 8 kt, straight into fragment registers ----
        short8 A0[8], A1[8], A2[8];
        const char* stab = wtab + s * 4608;
        #pragma unroll
        for (int kt = 0; kt < 8; ++kt) {
            const char* kr = stab + kt * 576;
            uint p0[4], p1[4], p2[4];
            #pragma unroll
            for (int up = 0; up < 4; ++up) {
                const float4 cA = *(const float4*)(kr + up * 32);
                const float4 cB = *(const float4*)(kr + up * 32 + 16);
                float pa = cA.w + cA.x * x0 + cA.y * x1 + cA.z * cc;
                float pb = cB.w + cB.x * x0 + cB.y * x1 + cB.z * cc;
                float ha = tanh_fast(pa), hb = tanh_fast(pb);
                float ga = 1.f - ha * ha, gb = 1.f - hb * hb;
                p0[up] = cvt_pk_bf16(ha, hb);
                p1[up] = cvt_pk_bf16(ga * cA.x, gb * cB.x);
                p2[up] = cvt_pk_bf16(ga * cA.y, gb * cB.y);
            }
            A0[kt] = __builtin_bit_cast(short8, (uintx4){p0[0], p0[1], p0[2], p0[3]});
            A1[kt] = __builtin_bit_cast(short8, (uintx4){p1[0], p1[1], p1[2], p1[3]});
            A2[kt] = __builtin_bit_cast(short8, (uintx4){p2[0], p2[1], p2[2], p2[3]});
        }

        // ---- GEMM: 4 N-passes (acc[3][4] = 48 regs), A-frags reused from regs ----
        float sv0[4] = {0,0,0,0}, sv1[4] = {0,0,0,0}, sdv[4] = {0,0,0,0};
        #pragma unroll
        for (int pass = 0; pass < 4; ++pass) {
            floatx4 acc0[4], acc1[4], acc2[4];
            #pragma unroll
            for (int n2 = 0; n2 < 4; ++n2) {
                acc0[n2] = (floatx4){0.f, 0.f, 0.f, 0.f};
                acc1[n2] = (floatx4){0.f, 0.f, 0.f, 0.f};
                acc2[n2] = (floatx4){0.f, 0.f, 0.f, 0.f};
            }
            #pragma unroll
            for (int kt = 0; kt < 8; ++kt) {
                #pragma unroll
                for (int n2 = 0; n2 < 4; ++n2) {
                    const int nt = pass * 4 + n2;
                    short8 bf = *(const short8*)(bbase + (size_t)(nt * 8 + kt) * 1024);
                    acc0[n2] = __builtin_amdgcn_mfma_f32_16x16x32_bf16(A0[kt], bf, acc0[n2], 0, 0, 0);
                    acc1[n2] = __builtin_amdgcn_mfma_f32_16x16x32_bf16(A1[kt], bf, acc1[n2], 0, 0, 0);
                    acc2[n2] = __builtin_amdgcn_mfma_f32_16x16x32_bf16(A2[kt], bf, acc2[n2], 0, 0, 0);
                }
            }
            // fused epilogue for this pass: C row = point q*4+r, col = j = nt*16+r15
            #pragma unroll
            for (int n2 = 0; n2 < 4; ++n2) {
                const int j = (pass * 4 + n2) * 16 + r15;
                const float4 w3c = *(const float4*)(sm + OFF_W3 + j * 16);
                #pragma unroll
                for (int r = 0; r < 4; ++r) {
                    float h2 = tanh_fast(acc0[n2][r] + w3c.z);
                    float g2 = 1.f - h2 * h2;
                    sv0[r] += h2 * w3c.x;
                    sv1[r] += h2 * w3c.y;
                    sdv[r] += g2 * (acc1[n2][r] * w3c.x + acc2[n2][r] * w3c.y);
                }
            }
        }

        // ---- wave-internal reduction over j (16 r15-lanes) + state update ----
        #pragma unroll
        for (int r = 0; r < 4; ++r) {
            float ta = dpp_sum16(sv0[r]);
            float tb = dpp_sum16(sv1[r]);
            float td = dpp_sum16(sdv[r]);
            if (r15 == 15) red[q * 4 + r] = (float4){ta, tb, td, 0.f};
        }
        __threadfence_block();                   // same-wave LDS RAW ordering
        const float4 rd = red[r15];              // totals for this lane's point
        x0 += (rd.x + b30) * osdt;
        x1 += (rd.y + b31) * osdt;
        cc += rd.z * osdt;
    }

    if (q == 0) {                                // one quad stores (state replicated)
        out[gp * 2 + 0] = x0;
        out[gp * 2 + 1] = x1;
        out[NPTS * 2 + gp] = cc;                 // log_det
    }
}

extern "C" void kernel_launch(void* const* d_in, const int* in_sizes, int n_in,
                              void* d_out, int out_size, void* d_ws, size_t ws_size,
                              hipStream_t stream) {
    const float* x   = (const float*)d_in[0];
    const float* z   = (const float*)d_in[1];
    const float* W1  = (const float*)d_in[2];
    const float* b1  = (const float*)d_in[3];
    const float* W2  = (const float*)d_in[4];
    const float* b2  = (const float*)d_in[5];
    const float* W3  = (const float*)d_in[6];
    const float* b3  = (const float*)d_in[7];
    const float* osc = (const float*)d_in[8];

    // ws layout: a1 [8192 f] @0 | rs [256 f] @32768B | wsw [65536 bf16] @33792B (~165KB)
    float* a1  = (float*)d_ws;
    float* rsv = (float*)((char*)d_ws + 32768);
    ushort* wsw = (ushort*)((char*)d_ws + 33792);

    static bool attr_set = false;
    if (!attr_set) {
        hipFuncSetAttribute((const void*)cnf_kernel,
                            hipFuncAttributeMaxDynamicSharedMemorySize, LDS_TOTAL);
        attr_set = true;
    }

    hipLaunchKernelGGL(prep_kernel, dim3(64), dim3(256), 0, stream, z, W1, b1, W2, a1, rsv, wsw);
    hipLaunchKernelGGL(cnf_kernel, dim3(512), dim3(512), LDS_TOTAL, stream,
                       x, W1, b2, W3, b3, osc, a1, rsv, wsw, (float*)d_out);
}

// Round 10
// 212.489 us; speedup vs baseline: 1.3532x; 1.3532x over previous
//
#include <hip/hip_runtime.h>

#define NPTS 65536          // B*N = 32*2048
#define HH 256
#define DIN 131
#define LAT 128
#define STEPS 5
#define DT 0.2f

typedef unsigned int uint;
typedef unsigned short ushort;
typedef __attribute__((ext_vector_type(8))) short short8;
typedef __attribute__((ext_vector_type(4))) float floatx4;
typedef __attribute__((ext_vector_type(4))) uint uintx4;

// Dynamic LDS layout (158208 B total):
//   smWsw   @ 0      : 131072 B  W2 bf16 fragments (now the MFMA *A* operand;
//                                wsw layout is already A-frag: row j = lane&15, k-slice = lane>>4)
//   smW1tab @ 131072 :  23040 B  [s][kt][q] groups of 8 unit-records {wa,wc,ra,ba_s} (16B),
//                                group stride 144B (pad -> the 4 quads hit distinct banks)
//   smW3    @ 154112 :   4096 B  float4[j] = {W3[0][j], W3[1][j], b2[j], 0}
#define OFF_W1TAB 131072
#define OFF_W3    154112
#define LDS_TOTAL 158208

__device__ __forceinline__ float tanh_fast(float x) {
    // tanh(x) = 1 - 2/(exp2(2x*log2e)+1); exact at both saturated ends.
    float e = __builtin_amdgcn_exp2f(x * 2.8853900817779268f);
    return 1.0f - 2.0f * __builtin_amdgcn_rcpf(e + 1.0f);
}

__device__ __forceinline__ ushort f2bf(float f) {
    uint u = __builtin_bit_cast(uint, f);
    u += 0x7fffu + ((u >> 16) & 1u);   // RNE
    return (ushort)(u >> 16);
}

// pack two f32 -> 2x bf16 (RNE) in one instruction; lo -> bits[15:0]
__device__ __forceinline__ uint cvt_pk_bf16(float lo, float hi) {
    uint r;
    asm("v_cvt_pk_bf16_f32 %0, %1, %2" : "=v"(r) : "v"(lo), "v"(hi));
    return r;
}

// ---- prep (unchanged; wsw layout doubles as the A-frag layout for W2-as-A):
//  a1[b][h] = b1[h] + sum_l z[b][l]*W1[h][3+l]   (t=0 bias)
//  rs[h] = sum_l W1[h][3+l]
//  wsw[((nt*8+kt)*64+lane)*8+j] = W2[nt*16+(lane&15)][kt*32+(lane>>4)*8+j]
__global__ void prep_kernel(const float* __restrict__ z, const float* __restrict__ W1,
                            const float* __restrict__ b1, const float* __restrict__ W2,
                            float* __restrict__ a1, float* __restrict__ rsv,
                            ushort* __restrict__ wsw)
{
    int tid = blockIdx.x * 256 + threadIdx.x;
    if (tid < 8192) {
        int b = tid >> 8, h = tid & 255;
        const float* wrow = W1 + h * DIN;
        const float* zb = z + b * LAT;
        float s = b1[h], r = 0.f;
        for (int l = 0; l < LAT; ++l) { float wv = wrow[3 + l]; s += wv * zb[l]; r += wv; }
        a1[tid] = s;
        if (b == 0) rsv[h] = r;
    } else {
        int t = tid - 8192;                    // 0..8191
        int lane = t & 63, kt = (t >> 6) & 7, nt = t >> 9;
        int n = nt * 16 + (lane & 15);
        int k = kt * 32 + (lane >> 4) * 8;
        const float* src = W2 + n * HH + k;
        ushort* dst = wsw + t * 8;
        #pragma unroll
        for (int j = 0; j < 8; ++j) dst[j] = f2bf(src[j]);
    }
}

// r10 = r9 wave-complete, barrier-free structure with MFMA ROLES SWAPPED
// (r9 postmortem: A-frags 96 + acc 48 + temps spilled ~14 regs -> 291MB scratch):
//   A operand = W2 tile from LDS (per-(nt,kt) ds_read; wsw layout is already A-frag)
//   B operand = activations built per-lane (identical build code to r9, which passed)
//   C = D[row=j][col=point]: each lane's acc regs are 4 j's of ITS OWN point (col=lane&15)
//     -> epilogue partials are 3 SCALARS, j-reduction = 2 __shfl_xor (no DPP chain/redbuf)
//     -> acc shrinks to [3][2] (24 regs, 8 nt-passes)
// Live set ~96 frags + 24 acc + ~40 misc = ~160 <= 256 cap (2 waves/EU).
// Two LDS base pointers keep every W2 ds_read offset < 64KB (static imm).
__global__ __launch_bounds__(512, 2) void cnf_kernel(
        const float* __restrict__ xin, const float* __restrict__ W1,
        const float* __restrict__ b2, const float* __restrict__ W3,
        const float* __restrict__ b3, const float* __restrict__ osc,
        const float* __restrict__ a1, const float* __restrict__ rsv,
        const ushort* __restrict__ wsw, float* __restrict__ out)
{
    extern __shared__ __align__(16) char sm[];

    const int tid = threadIdx.x;
    const int lane = tid & 63;
    const int w = tid >> 6;                      // 8 independent waves
    const int r15 = lane & 15;
    const int q = lane >> 4;
    const int blk = blockIdx.x;
    const int b = blk >> 4;                      // 16 blocks per batch (128 pts/block)

    // ---- stage W2 fragments: linear 131072B copy ----
    {
        uintx4* dst = (uintx4*)sm;
        const uintx4* src = (const uintx4*)wsw;
        #pragma unroll
        for (int i = 0; i < 16; ++i) dst[tid + i * 512] = src[tid + i * 512];
    }
    // ---- stage per-step layer-1 records + W3 projection table ----
    if (tid < HH) {
        const int h = tid;
        const int kt = h >> 5, rem = h & 31, qq = rem >> 3, u = rem & 7;
        const float wa = W1[h * DIN + 0];
        const float wc = W1[h * DIN + 1];
        const float wt = W1[h * DIN + 2];
        const float ra = rsv[h];
        const float ba = a1[b * HH + h];
        #pragma unroll
        for (int s = 0; s < STEPS; ++s) {
            float* rec = (float*)(sm + OFF_W1TAB + s * 4608 + kt * 576 + qq * 144 + u * 16);
            rec[0] = wa; rec[1] = wc; rec[2] = ra; rec[3] = ba + wt * ((float)s * DT);
        }
        float* w3r = (float*)(sm + OFF_W3 + h * 16);
        w3r[0] = W3[h]; w3r[1] = W3[HH + h]; w3r[2] = b2[h]; w3r[3] = 0.f;
    }

    // ---- per-lane state: point (lane&15), replicated across the 4 quads ----
    const int gp = blk * 128 + w * 16 + r15;
    float x0 = xin[gp * 2 + 0];
    float x1 = xin[gp * 2 + 1];
    float cc = 0.f;
    const float osdt = osc[0] * DT;
    const float b30 = b3[0], b31 = b3[1];

    __syncthreads();                             // the ONLY barrier

    const char* wtab = sm + OFF_W1TAB + q * 144; // this quad's unit records
    const char* wlo  = sm + (size_t)lane * 16;           // W2 frags, nt 0..7
    const char* whi  = sm + 65536 + (size_t)lane * 16;   // W2 frags, nt 8..15

    for (int s = 0; s < STEPS; ++s) {
        // ---- B-frag build (activations): 3 streams x 8 kt, verbatim r9 (verified) ----
        short8 B0[8], B1[8], B2[8];
        const char* stab = wtab + s * 4608;
        #pragma unroll
        for (int kt = 0; kt < 8; ++kt) {
            const char* kr = stab + kt * 576;
            uint p0[4], p1[4], p2[4];
            #pragma unroll
            for (int up = 0; up < 4; ++up) {
                const float4 cA = *(const float4*)(kr + up * 32);
                const float4 cB = *(const float4*)(kr + up * 32 + 16);
                float pa = cA.w + cA.x * x0 + cA.y * x1 + cA.z * cc;
                float pb = cB.w + cB.x * x0 + cB.y * x1 + cB.z * cc;
                float ha = tanh_fast(pa), hb = tanh_fast(pb);
                float ga = 1.f - ha * ha, gb = 1.f - hb * hb;
                p0[up] = cvt_pk_bf16(ha, hb);
                p1[up] = cvt_pk_bf16(ga * cA.x, gb * cB.x);
                p2[up] = cvt_pk_bf16(ga * cA.y, gb * cB.y);
            }
            B0[kt] = __builtin_bit_cast(short8, (uintx4){p0[0], p0[1], p0[2], p0[3]});
            B1[kt] = __builtin_bit_cast(short8, (uintx4){p1[0], p1[1], p1[2], p1[3]});
            B2[kt] = __builtin_bit_cast(short8, (uintx4){p2[0], p2[1], p2[2], p2[3]});
        }

        // ---- GEMM: 8 nt-passes, acc[3][2]=24 regs; W2 A-frags streamed from LDS ----
        float sv0 = 0.f, sv1 = 0.f, sdv = 0.f;    // per-lane (= per-point) partials
        #pragma unroll
        for (int pass = 0; pass < 8; ++pass) {
            floatx4 a0[2], a1v[2], a2[2];
            #pragma unroll
            for (int n2 = 0; n2 < 2; ++n2) {
                a0[n2]  = (floatx4){0.f, 0.f, 0.f, 0.f};
                a1v[n2] = (floatx4){0.f, 0.f, 0.f, 0.f};
                a2[n2]  = (floatx4){0.f, 0.f, 0.f, 0.f};
            }
            #pragma unroll
            for (int kt = 0; kt < 8; ++kt) {
                #pragma unroll
                for (int n2 = 0; n2 < 2; ++n2) {
                    const int nt = pass * 2 + n2;
                    const char* bp = (nt < 8 ? wlo : whi) + (size_t)(((nt & 7) * 8 + kt) * 1024);
                    short8 wf = *(const short8*)bp;      // one load feeds all 3 streams
                    a0[n2]  = __builtin_amdgcn_mfma_f32_16x16x32_bf16(wf, B0[kt], a0[n2],  0, 0, 0);
                    a1v[n2] = __builtin_amdgcn_mfma_f32_16x16x32_bf16(wf, B1[kt], a1v[n2], 0, 0, 0);
                    a2[n2]  = __builtin_amdgcn_mfma_f32_16x16x32_bf16(wf, B2[kt], a2[n2],  0, 0, 0);
                }
            }
            // epilogue: lane's acc reg r is j = nt*16 + q*4 + r of its own point
            #pragma unroll
            for (int n2 = 0; n2 < 2; ++n2) {
                const int nt = pass * 2 + n2;
                const float4* w3p = (const float4*)(sm + OFF_W3 + (size_t)(nt * 16 + q * 4) * 16);
                #pragma unroll
                for (int r = 0; r < 4; ++r) {
                    const float4 w3c = w3p[r];           // broadcast within quad
                    float h2 = tanh_fast(a0[n2][r] + w3c.z);
                    float g2 = 1.f - h2 * h2;
                    sv0 += h2 * w3c.x;
                    sv1 += h2 * w3c.y;
                    sdv += g2 * (a1v[n2][r] * w3c.x + a2[n2][r] * w3c.y);
                }
            }
        }

        // ---- cross-quad reduction (4 j-subsets) + state update, all in-wave ----
        sv0 += __shfl_xor(sv0, 16);  sv0 += __shfl_xor(sv0, 32);
        sv1 += __shfl_xor(sv1, 16);  sv1 += __shfl_xor(sv1, 32);
        sdv += __shfl_xor(sdv, 16);  sdv += __shfl_xor(sdv, 32);
        x0 += (sv0 + b30) * osdt;
        x1 += (sv1 + b31) * osdt;
        cc += sdv * osdt;
    }

    if (q == 0) {                                // one quad stores (state replicated)
        out[gp * 2 + 0] = x0;
        out[gp * 2 + 1] = x1;
        out[NPTS * 2 + gp] = cc;                 // log_det
    }
}

extern "C" void kernel_launch(void* const* d_in, const int* in_sizes, int n_in,
                              void* d_out, int out_size, void* d_ws, size_t ws_size,
                              hipStream_t stream) {
    const float* x   = (const float*)d_in[0];
    const float* z   = (const float*)d_in[1];
    const float* W1  = (const float*)d_in[2];
    const float* b1  = (const float*)d_in[3];
    const float* W2  = (const float*)d_in[4];
    const float* b2  = (const float*)d_in[5];
    const float* W3  = (const float*)d_in[6];
    const float* b3  = (const float*)d_in[7];
    const float* osc = (const float*)d_in[8];

    // ws layout: a1 [8192 f] @0 | rs [256 f] @32768B | wsw [65536 bf16] @33792B (~165KB)
    float* a1  = (float*)d_ws;
    float* rsv = (float*)((char*)d_ws + 32768);
    ushort* wsw = (ushort*)((char*)d_ws + 33792);

    static bool attr_set = false;
    if (!attr_set) {
        hipFuncSetAttribute((const void*)cnf_kernel,
                            hipFuncAttributeMaxDynamicSharedMemorySize, LDS_TOTAL);
        attr_set = true;
    }

    hipLaunchKernelGGL(prep_kernel, dim3(64), dim3(256), 0, stream, z, W1, b1, W2, a1, rsv, wsw);
    hipLaunchKernelGGL(cnf_kernel, dim3(512), dim3(512), LDS_TOTAL, stream,
                       x, W1, b2, W3, b3, osc, a1, rsv, wsw, (float*)d_out);
}